// Round 6
// baseline (1832.654 us; speedup 1.0000x reference)
//
#include <hip/hip_runtime.h>
#include <hip/hip_bf16.h>
#include <math.h>

// CommNetWork VALU kernel, MI355X gfx950 — fp32 in, fp32 OUT.
// Unified theory after R0-R5: ALL buffers are fp32 (reference dtype).
//  - R1/R2 NaN: fp32 inputs read as bf16 -> NaN encodings.
//  - R3/R4/R5 ~0.849: correct-ish bf16 values written into an fp32-read
//    output buffer (pairs packed into one fp32 word + unwritten tail).
//  - threshold 1.5625e-2 == 2% * max|ref| (fp32 relative), NOT bf16 ulps;
//    the "(bf16, ...)" label is a hardcoded harness string.
// This round: audited VALU pipeline, only change = fp32 output stores.

#define DIN 128
#define H0  256

__device__ __forceinline__ float bf2f(__hip_bfloat16 x) { return __bfloat162float(x); }
__device__ __forceinline__ __hip_bfloat16 f2bf(float x) { return __float2bfloat16(x); }
__device__ __forceinline__ float sigmoidf_(float x) { return 1.0f / (1.0f + expf(-x)); }

// unpack two bf16 (packed little-endian in a u32) to floats
__device__ __forceinline__ void bf2x(unsigned u, float& lo, float& hi) {
    union { unsigned i; float f; } a, b;
    a.i = u << 16;
    b.i = u & 0xffff0000u;
    lo = a.f;
    hi = b.f;
}

__global__ __launch_bounds__(512, 1) void commnet_diag(
    const float* __restrict__ obs,
    const float* __restrict__ W_enc, const float* __restrict__ b_enc,
    const float* __restrict__ W_obs, const float* __restrict__ b_obs,
    const float* __restrict__ W_ih,  const float* __restrict__ b_ih,
    const float* __restrict__ W_hh,  const float* __restrict__ b_hh,
    const float* __restrict__ W_val, const float* __restrict__ b_val,
    const float* __restrict__ W_dec, const float* __restrict__ b_dec,
    float* __restrict__ out)
{
    __shared__ __align__(16) __hip_bfloat16 TA[64 * H0];        // X -> C -> V
    __shared__ __align__(16) __hip_bfloat16 TB[64 * H0];        // H
    __shared__ __align__(16) unsigned char  TCraw[64 * H0 * 2]; // obs(f32) -> h'(bf16)
    __shared__ float colsum[2 * 256];

    float*          OBSp = (float*)TCraw;          // 64 x 128 fp32 = 32KB
    __hip_bfloat16* TC   = (__hip_bfloat16*)TCraw; // 64 x 256 bf16 = 32KB

    const int t    = threadIdx.x;
    const int row0 = blockIdx.x * 64;

    // ---- stage obs -> LDS (fp32, exact) ----
    for (int i = t; i < 64 * DIN; i += 512)
        OBSp[i] = obs[row0 * DIN + i];   // element (r,k) at r*128+k
    __syncthreads();

    // ---- X = relu(obs @ W_enc^T + b_enc) -> TA ----
    {
        const int c = t & 255, half = t >> 8;
        const float bias = b_enc[c];
        for (int ch = 0; ch < 4; ch++) {
            const int rbase = half * 32 + ch * 8;
            float acc[8] = {};
            for (int k = 0; k < DIN; k++) {
                const float w = W_enc[c * DIN + k];
                #pragma unroll
                for (int r8 = 0; r8 < 8; r8++)
                    acc[r8] += OBSp[(rbase + r8) * DIN + k] * w;
            }
            #pragma unroll
            for (int r8 = 0; r8 < 8; r8++)
                TA[(rbase + r8) * H0 + c] = f2bf(fmaxf(acc[r8] + bias, 0.0f));
        }
    }
    __syncthreads();

    // ---- H = X @ W_obs^T + b_obs -> TB ----
    {
        const int c = t & 255, half = t >> 8;
        const float bias = b_obs[c];
        for (int ch = 0; ch < 4; ch++) {
            const int rbase = half * 32 + ch * 8;
            float acc[8] = {};
            for (int k = 0; k < H0; k += 2) {
                const float w0 = W_obs[c * H0 + k];
                const float w1 = W_obs[c * H0 + k + 1];
                #pragma unroll
                for (int r8 = 0; r8 < 8; r8++) {
                    float a0, a1;
                    bf2x(*(const unsigned*)&TA[(rbase + r8) * H0 + k], a0, a1);
                    acc[r8] += a0 * w0 + a1 * w1;
                }
            }
            #pragma unroll
            for (int r8 = 0; r8 < 8; r8++)
                TB[(rbase + r8) * H0 + c] = f2bf(acc[r8] + bias);
        }
    }
    __syncthreads();

    // ---- comm: C = (colsum(H) - H) / 64 -> TA (X dead) ----
    {
        const int c = t & 255, half = t >> 8;
        float s = 0.0f;
        for (int r = half * 32; r < half * 32 + 32; r++)
            s += bf2f(TB[r * H0 + c]);
        colsum[half * 256 + c] = s;
        __syncthreads();
        const float tot = (colsum[c] + colsum[256 + c]) * (1.0f / 64.0f);
        for (int r = half * 32; r < half * 32 + 32; r++)
            TA[r * H0 + c] = f2bf(tot - bf2f(TB[r * H0 + c]) * (1.0f / 64.0f));
    }
    __syncthreads();

    // ---- GRU (PyTorch r,z,n): gi = C@W_ih^T+b_ih, gh = H@W_hh^T+b_hh ----
    {
        const int c = t & 255, half = t >> 8;
        const float bir = b_ih[c], biz = b_ih[c + 256], bin = b_ih[c + 512];
        const float bhr = b_hh[c], bhz = b_hh[c + 256], bhn = b_hh[c + 512];
        for (int ch = 0; ch < 4; ch++) {
            const int rbase = half * 32 + ch * 8;
            float aR[8] = {}, aZ[8] = {}, aNi[8] = {}, aNh[8] = {};
            for (int k = 0; k < H0; k += 2) {
                const float wir0 = W_ih[(c      ) * H0 + k], wir1 = W_ih[(c      ) * H0 + k + 1];
                const float wiz0 = W_ih[(c + 256) * H0 + k], wiz1 = W_ih[(c + 256) * H0 + k + 1];
                const float win0 = W_ih[(c + 512) * H0 + k], win1 = W_ih[(c + 512) * H0 + k + 1];
                const float whr0 = W_hh[(c      ) * H0 + k], whr1 = W_hh[(c      ) * H0 + k + 1];
                const float whz0 = W_hh[(c + 256) * H0 + k], whz1 = W_hh[(c + 256) * H0 + k + 1];
                const float whn0 = W_hh[(c + 512) * H0 + k], whn1 = W_hh[(c + 512) * H0 + k + 1];
                #pragma unroll
                for (int r8 = 0; r8 < 8; r8++) {
                    float c0, c1, h0, h1;
                    bf2x(*(const unsigned*)&TA[(rbase + r8) * H0 + k], c0, c1);
                    bf2x(*(const unsigned*)&TB[(rbase + r8) * H0 + k], h0, h1);
                    aR[r8]  += c0 * wir0 + c1 * wir1 + h0 * whr0 + h1 * whr1;
                    aZ[r8]  += c0 * wiz0 + c1 * wiz1 + h0 * whz0 + h1 * whz1;
                    aNi[r8] += c0 * win0 + c1 * win1;
                    aNh[r8] += h0 * whn0 + h1 * whn1;
                }
            }
            #pragma unroll
            for (int r8 = 0; r8 < 8; r8++) {
                const int r = rbase + r8;
                const float rr = sigmoidf_(aR[r8] + bir + bhr);
                const float zz = sigmoidf_(aZ[r8] + biz + bhz);
                const float nn = tanhf(aNi[r8] + bin + rr * (aNh[r8] + bhn));
                const float h  = bf2f(TB[r * H0 + c]);
                TC[r * H0 + c] = f2bf((1.0f - zz) * nn + zz * h);
            }
        }
    }
    __syncthreads();

    // ---- V = h' @ W_val^T + b_val -> TA (C dead) ----
    {
        const int c = t & 255, half = t >> 8;
        const float bias = b_val[c];
        for (int ch = 0; ch < 4; ch++) {
            const int rbase = half * 32 + ch * 8;
            float acc[8] = {};
            for (int k = 0; k < H0; k += 2) {
                const float w0 = W_val[c * H0 + k];
                const float w1 = W_val[c * H0 + k + 1];
                #pragma unroll
                for (int r8 = 0; r8 < 8; r8++) {
                    float a0, a1;
                    bf2x(*(const unsigned*)&TC[(rbase + r8) * H0 + k], a0, a1);
                    acc[r8] += a0 * w0 + a1 * w1;
                }
            }
            #pragma unroll
            for (int r8 = 0; r8 < 8; r8++)
                TA[(rbase + r8) * H0 + c] = f2bf(acc[r8] + bias);
        }
    }
    __syncthreads();

    // ---- OUT = V @ W_dec^T + b_dec -> global (fp32) ----
    {
        const int c  = t & 63;
        const int rg = t >> 6;
        const int rbase = rg * 8;
        const float bias = b_dec[c];
        float acc[8] = {};
        for (int k = 0; k < H0; k += 2) {
            const float w0 = W_dec[c * H0 + k];
            const float w1 = W_dec[c * H0 + k + 1];
            #pragma unroll
            for (int r8 = 0; r8 < 8; r8++) {
                float a0, a1;
                bf2x(*(const unsigned*)&TA[(rbase + r8) * H0 + k], a0, a1);
                acc[r8] += a0 * w0 + a1 * w1;
            }
        }
        #pragma unroll
        for (int r8 = 0; r8 < 8; r8++)
            out[(row0 + rbase + r8) * 64 + c] = acc[r8] + bias;
    }
}

extern "C" void kernel_launch(void* const* d_in, const int* in_sizes, int n_in,
                              void* d_out, int out_size, void* d_ws, size_t ws_size,
                              hipStream_t stream) {
    (void)d_ws; (void)ws_size; (void)out_size;
    // dict-order element counts:
    // obs, W_enc, b_enc, W_obs, b_obs, W_ih, b_ih, W_hh, b_hh, W_val, b_val, W_dec, b_dec
    static const int dictPat[13] = {2097152, 32768, 256, 65536, 256, 196608, 768,
                                    196608, 768, 65536, 256, 16384, 64};
    const void* p[13];
    bool isDict = (n_in >= 13);
    for (int i = 0; i < 13 && isDict; i++)
        if (in_sizes[i] != dictPat[i]) isDict = false;
    if (isDict) {
        for (int i = 0; i < 13; i++) p[i] = d_in[i];
    } else {
        // generic: find-by-size, dict-order ties
        bool used[64] = {};
        for (int i = 0; i < 13; i++) {
            p[i] = nullptr;
            for (int j = 0; j < n_in && j < 64; j++) {
                if (!used[j] && in_sizes[j] == dictPat[i]) {
                    p[i] = d_in[j]; used[j] = true; break;
                }
            }
            if (!p[i]) p[i] = d_in[(i < n_in) ? i : 0];
        }
    }

    commnet_diag<<<256, 512, 0, stream>>>(
        (const float*)p[0],
        (const float*)p[1],  (const float*)p[2],
        (const float*)p[3],  (const float*)p[4],
        (const float*)p[5],  (const float*)p[6],
        (const float*)p[7],  (const float*)p[8],
        (const float*)p[9],  (const float*)p[10],
        (const float*)p[11], (const float*)p[12],
        (float*)d_out);
}

// Round 7
// 153.493 us; speedup vs baseline: 11.9397x; 11.9397x over previous
//
#include <hip/hip_runtime.h>
#include <hip/hip_bf16.h>
#include <math.h>

// CommNetWork fused MFMA kernel, MI355X gfx950. fp32 in / fp32 out (R6-verified).
// One block per batch (256 blocks == 256 CUs), 512 threads (8 waves).
// prep_kernel: fp32 weights -> bf16 in d_ws (halves per-block L2 weight traffic).
// Main kernel: whole pipeline in 64KB LDS, 16x16x32 bf16 MFMA, fp32 biases/out.

typedef __bf16  bf16x8 __attribute__((ext_vector_type(8)));
typedef float   f32x4  __attribute__((ext_vector_type(4)));

#define DIN 128
#define H0  256

// ws element offsets (bf16) for converted weight matrices
#define O_WENC 0
#define O_WOBS 32768
#define O_WIH  98304
#define O_WHH  294912
#define O_WVAL 491520
#define O_WDEC 557056
#define W_TOT  573440   // elements; ws bytes needed = 1146880

__device__ __forceinline__ f32x4 mfma16(bf16x8 a, bf16x8 b, f32x4 c) {
    return __builtin_amdgcn_mfma_f32_16x16x32_bf16(a, b, c, 0, 0, 0);
}
__device__ __forceinline__ float bf2f(__hip_bfloat16 x) { return __bfloat162float(x); }
__device__ __forceinline__ __hip_bfloat16 f2bf(float x) { return __float2bfloat16(x); }
__device__ __forceinline__ float sigmoidf_(float x) { return 1.0f / (1.0f + expf(-x)); }

// weight fragment load: MODE 0 = bf16 (from ws), MODE 1 = fp32 (direct global)
template<int MODE>
__device__ __forceinline__ bf16x8 g8(const void* p, int idx) {
    if constexpr (MODE == 0) {
        return *(const bf16x8*)((const __hip_bfloat16*)p + idx);
    } else {
        const float* f = (const float*)p + idx;
        f32x4 a = *(const f32x4*)f;
        f32x4 b = *(const f32x4*)(f + 4);
        bf16x8 r;
        #pragma unroll
        for (int j = 0; j < 4; j++) { r[j] = (__bf16)a[j]; r[j + 4] = (__bf16)b[j]; }
        return r;
    }
}

// element (r,k) of a swizzled 64x256 bf16 tile (32 chunks of 8 per row)
__device__ __forceinline__ int tadr(int r, int k) {
    return (r << 8) + ((((k >> 3) ^ r) & 31) << 3) + (k & 7);
}
// element (r,k) of the swizzled 64x128 obs tile (16 chunks of 8 per row)
__device__ __forceinline__ int oadr(int r, int k) {
    return (r << 7) + ((((k >> 3) ^ r) & 15) << 3) + (k & 7);
}

// ---- prep: convert 6 weight matrices fp32 -> bf16 into ws ----
__global__ void prep_kernel(const float* __restrict__ W_enc,
                            const float* __restrict__ W_obs,
                            const float* __restrict__ W_ih,
                            const float* __restrict__ W_hh,
                            const float* __restrict__ W_val,
                            const float* __restrict__ W_dec,
                            __hip_bfloat16* __restrict__ ws) {
    const int stride = gridDim.x * blockDim.x;
    for (int i = blockIdx.x * blockDim.x + threadIdx.x; i < W_TOT; i += stride) {
        const float* src; int off;
        if      (i < O_WOBS) { src = W_enc; off = O_WENC; }
        else if (i < O_WIH)  { src = W_obs; off = O_WOBS; }
        else if (i < O_WHH)  { src = W_ih;  off = O_WIH;  }
        else if (i < O_WVAL) { src = W_hh;  off = O_WHH;  }
        else if (i < O_WDEC) { src = W_val; off = O_WVAL; }
        else                 { src = W_dec; off = O_WDEC; }
        ws[i] = f2bf(src[i - off]);
    }
}

template<int MODE>
__global__ __launch_bounds__(512, 2) void commnet_mfma(
    const void* __restrict__ W_enc, const void* __restrict__ W_obs,
    const void* __restrict__ W_ih,  const void* __restrict__ W_hh,
    const void* __restrict__ W_val, const void* __restrict__ W_dec,
    const float* __restrict__ b_enc, const float* __restrict__ b_obs,
    const float* __restrict__ b_ih,  const float* __restrict__ b_hh,
    const float* __restrict__ b_val, const float* __restrict__ b_dec,
    const float* __restrict__ obs,   float* __restrict__ out)
{
    __shared__ __align__(16) __hip_bfloat16 T0[64 * 256];  // X1 -> (sums,C) -> V
    __shared__ __align__(16) __hip_bfloat16 T1[64 * 256];  // obs -> H -> h'

    const int tid  = threadIdx.x;
    const int wave = tid >> 6;
    const int lane = tid & 63;
    const int quad = lane >> 4;
    const int lc   = lane & 15;          // tile col (n) / A-frag row (m)
    const int row0 = blockIdx.x * 64;    // global row base for this batch
    const int ko16 = quad * 8;           // k offset of this lane's fragment

    // ---- stage obs (fp32 global) -> bf16 swizzled T1 ----
    for (int i = tid; i < 64 * DIN / 8; i += 512) {
        const int r = i >> 4;
        const int c = (i & 15) << 3;
        const float* src = obs + (row0 + r) * DIN + c;
        f32x4 a = *(const f32x4*)src;
        f32x4 b = *(const f32x4*)(src + 4);
        bf16x8 v;
        #pragma unroll
        for (int j = 0; j < 4; j++) { v[j] = (__bf16)a[j]; v[j + 4] = (__bf16)b[j]; }
        *(bf16x8*)&T1[oadr(r, c)] = v;
    }
    __syncthreads();

    // ---- stage 1: X1 = relu(obs @ W_enc^T + b_enc) -> T0 ----
    {
        const int n0 = (wave    ) * 16 + lc;
        const int n1 = (wave + 8) * 16 + lc;
        f32x4 acc0[4] = {}, acc1[4] = {};
        for (int k0 = 0; k0 < DIN; k0 += 32) {
            const int kk = k0 + ko16;
            bf16x8 a[4];
            #pragma unroll
            for (int rt = 0; rt < 4; rt++)
                a[rt] = *(const bf16x8*)&T1[oadr(rt * 16 + lc, kk)];
            bf16x8 b0 = g8<MODE>(W_enc, n0 * DIN + kk);
            bf16x8 b1 = g8<MODE>(W_enc, n1 * DIN + kk);
            #pragma unroll
            for (int rt = 0; rt < 4; rt++) {
                acc0[rt] = mfma16(a[rt], b0, acc0[rt]);
                acc1[rt] = mfma16(a[rt], b1, acc1[rt]);
            }
        }
        const float bias0 = b_enc[n0];
        const float bias1 = b_enc[n1];
        #pragma unroll
        for (int rt = 0; rt < 4; rt++)
            #pragma unroll
            for (int i = 0; i < 4; i++) {
                const int row = rt * 16 + quad * 4 + i;
                T0[tadr(row, n0)] = f2bf(fmaxf(acc0[rt][i] + bias0, 0.0f));
                T0[tadr(row, n1)] = f2bf(fmaxf(acc1[rt][i] + bias1, 0.0f));
            }
    }
    __syncthreads();

    // ---- stage 2: H = X1 @ W_obs^T + b_obs -> T1 (obs region dead) ----
    {
        const int n0 = (wave    ) * 16 + lc;
        const int n1 = (wave + 8) * 16 + lc;
        f32x4 acc0[4] = {}, acc1[4] = {};
        for (int k0 = 0; k0 < H0; k0 += 32) {
            const int kk = k0 + ko16;
            bf16x8 a[4];
            #pragma unroll
            for (int rt = 0; rt < 4; rt++)
                a[rt] = *(const bf16x8*)&T0[tadr(rt * 16 + lc, kk)];
            bf16x8 b0 = g8<MODE>(W_obs, n0 * H0 + kk);
            bf16x8 b1 = g8<MODE>(W_obs, n1 * H0 + kk);
            #pragma unroll
            for (int rt = 0; rt < 4; rt++) {
                acc0[rt] = mfma16(a[rt], b0, acc0[rt]);
                acc1[rt] = mfma16(a[rt], b1, acc1[rt]);
            }
        }
        const float bias0 = b_obs[n0];
        const float bias1 = b_obs[n1];
        #pragma unroll
        for (int rt = 0; rt < 4; rt++)
            #pragma unroll
            for (int i = 0; i < 4; i++) {
                const int row = rt * 16 + quad * 4 + i;
                T1[tadr(row, n0)] = f2bf(acc0[rt][i] + bias0);
                T1[tadr(row, n1)] = f2bf(acc1[rt][i] + bias1);
            }
    }
    __syncthreads();

    // ---- comm: C = (colsum(H) - H) / 64 -> T0 (X1 dead) ----
    {
        float* sSumF = (float*)T0;          // overlays dead X1 rows 0..3
        const int col  = tid & 255;
        const int half = tid >> 8;
        float s = 0.0f;
        for (int r = half * 32; r < half * 32 + 32; r++)
            s += bf2f(T1[tadr(r, col)]);
        sSumF[half * 256 + col] = s;
        __syncthreads();
        const float tot = (sSumF[col] + sSumF[256 + col]) * (1.0f / 64.0f);
        __syncthreads();
        for (int r = half * 32; r < half * 32 + 32; r++)
            T0[tadr(r, col)] = f2bf(tot - bf2f(T1[tadr(r, col)]) * (1.0f / 64.0f));
    }
    __syncthreads();

    // ---- GRU: r/z fuse gi+gh in one acc; h' written in place over H ----
    {
        f32x4 ar[2][4] = {}, az[2][4] = {}, ani[2][4] = {}, anh[2][4] = {};
        for (int k0 = 0; k0 < H0; k0 += 32) {
            const int kk = k0 + ko16;
            bf16x8 aC[4], aH[4];
            #pragma unroll
            for (int rt = 0; rt < 4; rt++) {
                aC[rt] = *(const bf16x8*)&T0[tadr(rt * 16 + lc, kk)];
                aH[rt] = *(const bf16x8*)&T1[tadr(rt * 16 + lc, kk)];
            }
            #pragma unroll
            for (int c2 = 0; c2 < 2; c2++) {
                const int n = (wave + 8 * c2) * 16 + lc;
                bf16x8 bir = g8<MODE>(W_ih, (n      ) * H0 + kk);
                bf16x8 biz = g8<MODE>(W_ih, (n + 256) * H0 + kk);
                bf16x8 bin = g8<MODE>(W_ih, (n + 512) * H0 + kk);
                bf16x8 bhr = g8<MODE>(W_hh, (n      ) * H0 + kk);
                bf16x8 bhz = g8<MODE>(W_hh, (n + 256) * H0 + kk);
                bf16x8 bhn = g8<MODE>(W_hh, (n + 512) * H0 + kk);
                #pragma unroll
                for (int rt = 0; rt < 4; rt++) {
                    ar[c2][rt]  = mfma16(aC[rt], bir, ar[c2][rt]);
                    ar[c2][rt]  = mfma16(aH[rt], bhr, ar[c2][rt]);
                    az[c2][rt]  = mfma16(aC[rt], biz, az[c2][rt]);
                    az[c2][rt]  = mfma16(aH[rt], bhz, az[c2][rt]);
                    ani[c2][rt] = mfma16(aC[rt], bin, ani[c2][rt]);
                    anh[c2][rt] = mfma16(aH[rt], bhn, anh[c2][rt]);
                }
            }
        }
        __syncthreads();   // all MFMA reads of C (T0) and H (T1) complete
        #pragma unroll
        for (int c2 = 0; c2 < 2; c2++) {
            const int n = (wave + 8 * c2) * 16 + lc;
            const float br = b_ih[n      ] + b_hh[n      ];
            const float bz = b_ih[n + 256] + b_hh[n + 256];
            const float bi = b_ih[n + 512];
            const float bh = b_hh[n + 512];
            #pragma unroll
            for (int rt = 0; rt < 4; rt++)
                #pragma unroll
                for (int i = 0; i < 4; i++) {
                    const int row = rt * 16 + quad * 4 + i;
                    const float r  = sigmoidf_(ar[c2][rt][i] + br);
                    const float z  = sigmoidf_(az[c2][rt][i] + bz);
                    const float nn = tanhf(ani[c2][rt][i] + bi + r * (anh[c2][rt][i] + bh));
                    const float h  = bf2f(T1[tadr(row, n)]);
                    T1[tadr(row, n)] = f2bf((1.0f - z) * nn + z * h);
                }
        }
    }
    __syncthreads();

    // ---- value head: V = h' @ W_val^T + b_val -> T0 (C dead) ----
    {
        const int n0 = (wave    ) * 16 + lc;
        const int n1 = (wave + 8) * 16 + lc;
        f32x4 acc0[4] = {}, acc1[4] = {};
        for (int k0 = 0; k0 < H0; k0 += 32) {
            const int kk = k0 + ko16;
            bf16x8 a[4];
            #pragma unroll
            for (int rt = 0; rt < 4; rt++)
                a[rt] = *(const bf16x8*)&T1[tadr(rt * 16 + lc, kk)];
            bf16x8 b0 = g8<MODE>(W_val, n0 * H0 + kk);
            bf16x8 b1 = g8<MODE>(W_val, n1 * H0 + kk);
            #pragma unroll
            for (int rt = 0; rt < 4; rt++) {
                acc0[rt] = mfma16(a[rt], b0, acc0[rt]);
                acc1[rt] = mfma16(a[rt], b1, acc1[rt]);
            }
        }
        const float bias0 = b_val[n0];
        const float bias1 = b_val[n1];
        #pragma unroll
        for (int rt = 0; rt < 4; rt++)
            #pragma unroll
            for (int i = 0; i < 4; i++) {
                const int row = rt * 16 + quad * 4 + i;
                T0[tadr(row, n0)] = f2bf(acc0[rt][i] + bias0);
                T0[tadr(row, n1)] = f2bf(acc1[rt][i] + bias1);
            }
    }
    __syncthreads();

    // ---- decode: OUT = V @ W_dec^T + b_dec -> global fp32 ----
    {
        const int ct  = wave & 3;          // 4 col-tiles (H2=64)
        const int rtb = (wave >> 2) * 2;   // waves 0-3: rows 0..31, 4-7: 32..63
        const int n   = ct * 16 + lc;
        f32x4 acc[2] = {};
        for (int k0 = 0; k0 < H0; k0 += 32) {
            const int kk = k0 + ko16;
            bf16x8 bf = g8<MODE>(W_dec, n * H0 + kk);
            #pragma unroll
            for (int j = 0; j < 2; j++) {
                bf16x8 af = *(const bf16x8*)&T0[tadr((rtb + j) * 16 + lc, kk)];
                acc[j] = mfma16(af, bf, acc[j]);
            }
        }
        const float bias = b_dec[n];
        #pragma unroll
        for (int j = 0; j < 2; j++)
            #pragma unroll
            for (int i = 0; i < 4; i++) {
                const int row = (rtb + j) * 16 + quad * 4 + i;
                out[(row0 + row) * 64 + n] = acc[j][i] + bias;
            }
    }
}

extern "C" void kernel_launch(void* const* d_in, const int* in_sizes, int n_in,
                              void* d_out, int out_size, void* d_ws, size_t ws_size,
                              hipStream_t stream) {
    (void)in_sizes; (void)n_in; (void)out_size;
    const float* obs   = (const float*)d_in[0];
    const float* W_enc = (const float*)d_in[1];  const float* b_enc = (const float*)d_in[2];
    const float* W_obs = (const float*)d_in[3];  const float* b_obs = (const float*)d_in[4];
    const float* W_ih  = (const float*)d_in[5];  const float* b_ih  = (const float*)d_in[6];
    const float* W_hh  = (const float*)d_in[7];  const float* b_hh  = (const float*)d_in[8];
    const float* W_val = (const float*)d_in[9];  const float* b_val = (const float*)d_in[10];
    const float* W_dec = (const float*)d_in[11]; const float* b_dec = (const float*)d_in[12];
    float* out = (float*)d_out;

    if (ws_size >= (size_t)W_TOT * 2) {
        __hip_bfloat16* ws = (__hip_bfloat16*)d_ws;
        prep_kernel<<<512, 256, 0, stream>>>(W_enc, W_obs, W_ih, W_hh, W_val, W_dec, ws);
        commnet_mfma<0><<<256, 512, 0, stream>>>(
            ws + O_WENC, ws + O_WOBS, ws + O_WIH, ws + O_WHH, ws + O_WVAL, ws + O_WDEC,
            b_enc, b_obs, b_ih, b_hh, b_val, b_dec, obs, out);
    } else {
        commnet_mfma<1><<<256, 512, 0, stream>>>(
            W_enc, W_obs, W_ih, W_hh, W_val, W_dec,
            b_enc, b_obs, b_ih, b_hh, b_val, b_dec, obs, out);
    }
}

// Round 8
// 128.382 us; speedup vs baseline: 14.2750x; 1.1956x over previous
//
#include <hip/hip_runtime.h>
#include <hip/hip_bf16.h>
#include <math.h>

// CommNetWork fused MFMA kernel v2, MI355X gfx950. fp32 in / fp32 out.
// R7 post-mortem: VGPR_Count=128 + WRITE_SIZE=50MB (vs 4MB output) = accumulator
// spill to scratch. v2 keeps live accumulators <=24 f32x4 per region by
// splitting each GEMM stage into two sequential column-half passes, and folds
// the comm-mean into the GRU via colsum(H@W^T) (in-register shuffle reduce).

typedef __bf16  bf16x8 __attribute__((ext_vector_type(8)));
typedef float   f32x4  __attribute__((ext_vector_type(4)));

#define DIN 128
#define H0  256

// ws element offsets (bf16) for converted weight matrices
#define O_WENC 0
#define O_WOBS 32768
#define O_WIH  98304
#define O_WHH  294912
#define O_WVAL 491520
#define O_WDEC 557056
#define W_TOT  573440   // elements; ws bytes needed = 1146880

__device__ __forceinline__ f32x4 mfma16(bf16x8 a, bf16x8 b, f32x4 c) {
    return __builtin_amdgcn_mfma_f32_16x16x32_bf16(a, b, c, 0, 0, 0);
}
__device__ __forceinline__ float bf2f(__hip_bfloat16 x) { return __bfloat162float(x); }
__device__ __forceinline__ __hip_bfloat16 f2bf(float x) { return __float2bfloat16(x); }
__device__ __forceinline__ float sigmoidf_(float x) { return 1.0f / (1.0f + expf(-x)); }

__device__ __forceinline__ bf16x8 w8(const __hip_bfloat16* p, int idx) {
    return *(const bf16x8*)(p + idx);
}

// element (r,k) of a swizzled 64x256 bf16 tile (32 chunks of 8 per row)
__device__ __forceinline__ int tadr(int r, int k) {
    return (r << 8) + ((((k >> 3) ^ r) & 31) << 3) + (k & 7);
}
// element (r,k) of the swizzled 64x128 obs tile (16 chunks of 8 per row)
__device__ __forceinline__ int oadr(int r, int k) {
    return (r << 7) + ((((k >> 3) ^ r) & 15) << 3) + (k & 7);
}

// ---- prep: convert 6 weight matrices fp32 -> bf16 into ws (vectorized) ----
// 71680 chunks of 8 elements; grid 280 x 256 covers exactly.
__global__ __launch_bounds__(256) void prep_kernel(
    const float* __restrict__ W_enc, const float* __restrict__ W_obs,
    const float* __restrict__ W_ih,  const float* __restrict__ W_hh,
    const float* __restrict__ W_val, const float* __restrict__ W_dec,
    __hip_bfloat16* __restrict__ ws)
{
    const int i = (blockIdx.x * 256 + threadIdx.x) * 8;
    if (i >= W_TOT) return;
    const float* src; int off;
    if      (i < O_WOBS) { src = W_enc; off = O_WENC; }
    else if (i < O_WIH)  { src = W_obs; off = O_WOBS; }
    else if (i < O_WHH)  { src = W_ih;  off = O_WIH;  }
    else if (i < O_WVAL) { src = W_hh;  off = O_WHH;  }
    else if (i < O_WDEC) { src = W_val; off = O_WVAL; }
    else                 { src = W_dec; off = O_WDEC; }
    const float* f = src + (i - off);
    f32x4 a = *(const f32x4*)f;
    f32x4 b = *(const f32x4*)(f + 4);
    bf16x8 v;
    #pragma unroll
    for (int j = 0; j < 4; j++) { v[j] = (__bf16)a[j]; v[j + 4] = (__bf16)b[j]; }
    *(bf16x8*)(ws + i) = v;
}

__global__ __launch_bounds__(512, 2) void commnet_mfma(
    const __hip_bfloat16* __restrict__ ws,
    const float* __restrict__ b_enc, const float* __restrict__ b_obs,
    const float* __restrict__ b_ih,  const float* __restrict__ b_hh,
    const float* __restrict__ b_val, const float* __restrict__ b_dec,
    const float* __restrict__ obs,   float* __restrict__ out)
{
    __shared__ __align__(16) __hip_bfloat16 T0[64 * 256];  // X1 -> h' 
    __shared__ __align__(16) __hip_bfloat16 T1[64 * 256];  // obs -> H -> V

    const __hip_bfloat16* W_enc = ws + O_WENC;
    const __hip_bfloat16* W_obs = ws + O_WOBS;
    const __hip_bfloat16* W_ih  = ws + O_WIH;
    const __hip_bfloat16* W_hh  = ws + O_WHH;
    const __hip_bfloat16* W_val = ws + O_WVAL;
    const __hip_bfloat16* W_dec = ws + O_WDEC;

    const int tid  = threadIdx.x;
    const int wave = tid >> 6;
    const int lane = tid & 63;
    const int quad = lane >> 4;
    const int lc   = lane & 15;          // tile col (n) / A-frag row (m)
    const int row0 = blockIdx.x * 64;    // global row base for this batch
    const int ko16 = quad * 8;           // k offset of this lane's fragment

    // ---- stage obs (fp32 global) -> bf16 swizzled T1 ----
    for (int i = tid; i < 64 * DIN / 8; i += 512) {
        const int r = i >> 4;
        const int c = (i & 15) << 3;
        const float* src = obs + (row0 + r) * DIN + c;
        f32x4 a = *(const f32x4*)src;
        f32x4 b = *(const f32x4*)(src + 4);
        bf16x8 v;
        #pragma unroll
        for (int j = 0; j < 4; j++) { v[j] = (__bf16)a[j]; v[j + 4] = (__bf16)b[j]; }
        *(bf16x8*)&T1[oadr(r, c)] = v;
    }
    __syncthreads();

    // ---- stage 1: X1 = relu(obs @ W_enc^T + b_enc) -> T0 (2 col-half passes) ----
    #pragma unroll
    for (int cp = 0; cp < 2; cp++) {
        const int n = (wave + 8 * cp) * 16 + lc;
        const float bias = b_enc[n];
        f32x4 acc[4] = {};
        #pragma unroll
        for (int k0 = 0; k0 < DIN; k0 += 32) {
            const int kk = k0 + ko16;
            bf16x8 b = w8(W_enc, n * DIN + kk);
            #pragma unroll
            for (int rt = 0; rt < 4; rt++) {
                bf16x8 a = *(const bf16x8*)&T1[oadr(rt * 16 + lc, kk)];
                acc[rt] = mfma16(a, b, acc[rt]);
            }
        }
        #pragma unroll
        for (int rt = 0; rt < 4; rt++)
            #pragma unroll
            for (int i = 0; i < 4; i++) {
                const int row = rt * 16 + quad * 4 + i;
                T0[tadr(row, n)] = f2bf(fmaxf(acc[rt][i] + bias, 0.0f));
            }
    }
    __syncthreads();

    // ---- stage 2: H = X1 @ W_obs^T + b_obs -> T1 (obs region dead) ----
    #pragma unroll
    for (int cp = 0; cp < 2; cp++) {
        const int n = (wave + 8 * cp) * 16 + lc;
        const float bias = b_obs[n];
        f32x4 acc[4] = {};
        #pragma unroll 2
        for (int k0 = 0; k0 < H0; k0 += 32) {
            const int kk = k0 + ko16;
            bf16x8 b = w8(W_obs, n * H0 + kk);
            #pragma unroll
            for (int rt = 0; rt < 4; rt++) {
                bf16x8 a = *(const bf16x8*)&T0[tadr(rt * 16 + lc, kk)];
                acc[rt] = mfma16(a, b, acc[rt]);
            }
        }
        #pragma unroll
        for (int rt = 0; rt < 4; rt++)
            #pragma unroll
            for (int i = 0; i < 4; i++) {
                const int row = rt * 16 + quad * 4 + i;
                T1[tadr(row, n)] = f2bf(acc[rt][i] + bias);
            }
    }
    __syncthreads();

    // ---- GRU with folded comm (2 col-half passes, h' -> T0) ----
    // gi = C@W_ih^T + b_ih, C = (colsum(H) - H)/64
    //    = (colsum(Gi) - Gi)/64 + b_ih  with Gi = H@W_ih^T  (colsum commutes).
    // Each wave owns its 16 columns for ALL 64 rows: colsum(Gi) = in-lane sum
    // over rt,i + shfl_xor over the 4 quads.
    #pragma unroll
    for (int cp = 0; cp < 2; cp++) {
        const int n = (wave + 8 * cp) * 16 + lc;
        const float bir = b_ih[n], biz = b_ih[n + 256], bin = b_ih[n + 512];
        const float bhr = b_hh[n], bhz = b_hh[n + 256], bhn = b_hh[n + 512];
        f32x4 gir[4] = {}, giz[4] = {}, gin[4] = {};
        f32x4 ghr[4] = {}, ghz[4] = {}, ghn[4] = {};
        #pragma unroll 2
        for (int k0 = 0; k0 < H0; k0 += 32) {
            const int kk = k0 + ko16;
            bf16x8 bir8 = w8(W_ih, (n      ) * H0 + kk);
            bf16x8 biz8 = w8(W_ih, (n + 256) * H0 + kk);
            bf16x8 bin8 = w8(W_ih, (n + 512) * H0 + kk);
            bf16x8 bhr8 = w8(W_hh, (n      ) * H0 + kk);
            bf16x8 bhz8 = w8(W_hh, (n + 256) * H0 + kk);
            bf16x8 bhn8 = w8(W_hh, (n + 512) * H0 + kk);
            #pragma unroll
            for (int rt = 0; rt < 4; rt++) {
                bf16x8 aH = *(const bf16x8*)&T1[tadr(rt * 16 + lc, kk)];
                gir[rt] = mfma16(aH, bir8, gir[rt]);
                giz[rt] = mfma16(aH, biz8, giz[rt]);
                gin[rt] = mfma16(aH, bin8, gin[rt]);
                ghr[rt] = mfma16(aH, bhr8, ghr[rt]);
                ghz[rt] = mfma16(aH, bhz8, ghz[rt]);
                ghn[rt] = mfma16(aH, bhn8, ghn[rt]);
            }
        }
        // column sums of the gi streams (over all 64 rows)
        float Sr = 0.0f, Sz = 0.0f, Sn = 0.0f;
        #pragma unroll
        for (int rt = 0; rt < 4; rt++)
            #pragma unroll
            for (int i = 0; i < 4; i++) {
                Sr += gir[rt][i]; Sz += giz[rt][i]; Sn += gin[rt][i];
            }
        Sr += __shfl_xor(Sr, 16); Sr += __shfl_xor(Sr, 32);
        Sz += __shfl_xor(Sz, 16); Sz += __shfl_xor(Sz, 32);
        Sn += __shfl_xor(Sn, 16); Sn += __shfl_xor(Sn, 32);

        #pragma unroll
        for (int rt = 0; rt < 4; rt++)
            #pragma unroll
            for (int i = 0; i < 4; i++) {
                const int row = rt * 16 + quad * 4 + i;
                const float gi_r = (Sr - gir[rt][i]) * (1.0f / 64.0f) + bir;
                const float gi_z = (Sz - giz[rt][i]) * (1.0f / 64.0f) + biz;
                const float gi_n = (Sn - gin[rt][i]) * (1.0f / 64.0f) + bin;
                const float r  = sigmoidf_(gi_r + ghr[rt][i] + bhr);
                const float z  = sigmoidf_(gi_z + ghz[rt][i] + bhz);
                const float nn = tanhf(gi_n + r * (ghn[rt][i] + bhn));
                const float h  = bf2f(T1[tadr(row, n)]);
                T0[tadr(row, n)] = f2bf((1.0f - z) * nn + z * h);
            }
    }
    __syncthreads();

    // ---- value head: V = h' @ W_val^T + b_val -> T1 (H dead) ----
    #pragma unroll
    for (int cp = 0; cp < 2; cp++) {
        const int n = (wave + 8 * cp) * 16 + lc;
        const float bias = b_val[n];
        f32x4 acc[4] = {};
        #pragma unroll 2
        for (int k0 = 0; k0 < H0; k0 += 32) {
            const int kk = k0 + ko16;
            bf16x8 b = w8(W_val, n * H0 + kk);
            #pragma unroll
            for (int rt = 0; rt < 4; rt++) {
                bf16x8 a = *(const bf16x8*)&T0[tadr(rt * 16 + lc, kk)];
                acc[rt] = mfma16(a, b, acc[rt]);
            }
        }
        #pragma unroll
        for (int rt = 0; rt < 4; rt++)
            #pragma unroll
            for (int i = 0; i < 4; i++) {
                const int row = rt * 16 + quad * 4 + i;
                T1[tadr(row, n)] = f2bf(acc[rt][i] + bias);
            }
    }
    __syncthreads();

    // ---- decode: OUT = V @ W_dec^T + b_dec -> global fp32 ----
    {
        const int ct  = wave & 3;          // 4 col-tiles (H2=64)
        const int rtb = (wave >> 2) * 2;   // waves 0-3: rows 0..31, 4-7: 32..63
        const int n   = ct * 16 + lc;
        const float bias = b_dec[n];
        f32x4 acc[2] = {};
        #pragma unroll 2
        for (int k0 = 0; k0 < H0; k0 += 32) {
            const int kk = k0 + ko16;
            bf16x8 b = w8(W_dec, n * H0 + kk);
            #pragma unroll
            for (int j = 0; j < 2; j++) {
                bf16x8 a = *(const bf16x8*)&T1[tadr((rtb + j) * 16 + lc, kk)];
                acc[j] = mfma16(a, b, acc[j]);
            }
        }
        #pragma unroll
        for (int j = 0; j < 2; j++)
            #pragma unroll
            for (int i = 0; i < 4; i++) {
                const int row = (rtb + j) * 16 + quad * 4 + i;
                out[(row0 + row) * 64 + n] = acc[j][i] + bias;
            }
    }
}

extern "C" void kernel_launch(void* const* d_in, const int* in_sizes, int n_in,
                              void* d_out, int out_size, void* d_ws, size_t ws_size,
                              hipStream_t stream) {
    (void)in_sizes; (void)n_in; (void)out_size; (void)ws_size;
    const float* obs   = (const float*)d_in[0];
    const float* W_enc = (const float*)d_in[1];  const float* b_enc = (const float*)d_in[2];
    const float* W_obs = (const float*)d_in[3];  const float* b_obs = (const float*)d_in[4];
    const float* W_ih  = (const float*)d_in[5];  const float* b_ih  = (const float*)d_in[6];
    const float* W_hh  = (const float*)d_in[7];  const float* b_hh  = (const float*)d_in[8];
    const float* W_val = (const float*)d_in[9];  const float* b_val = (const float*)d_in[10];
    const float* W_dec = (const float*)d_in[11]; const float* b_dec = (const float*)d_in[12];
    float* out = (float*)d_out;
    __hip_bfloat16* ws = (__hip_bfloat16*)d_ws;

    prep_kernel<<<280, 256, 0, stream>>>(W_enc, W_obs, W_ih, W_hh, W_val, W_dec, ws);
    commnet_mfma<<<256, 512, 0, stream>>>(
        ws, b_enc, b_obs, b_ih, b_hh, b_val, b_dec, obs, out);
}